// Round 8
// baseline (504.793 us; speedup 1.0000x reference)
//
#include <hip/hip_runtime.h>
#include <hip/hip_bf16.h>

#define B_   128
#define TE_  512
#define TD_  128
#define EH_  512
#define DH_  512
#define KC_  7
#define CC_  105
#define G_   2048   // 4*DH
#define KX_  617    // EH + CC
#define KP_  640    // padded K for gates GEMM
#define GNT  10     // KP_/64 K-tiles for gates GEMM

typedef __attribute__((ext_vector_type(8))) short bf16x8;
typedef __attribute__((ext_vector_type(4))) float f32x4;

__device__ __forceinline__ float sigm(float x){ return 1.f/(1.f + __expf(-x)); }
__device__ __forceinline__ float tanhf_fast(float x){
  float e = __expf(2.f*x);
  return 1.f - 2.f/(e + 1.f);
}

// fp32 -> bf16 (RNE)
__device__ __forceinline__ unsigned short f2bf(float f){
  unsigned int u = __float_as_uint(f);
  unsigned int r = (u + 0x7fffu + ((u >> 16) & 1u)) >> 16;
  return (unsigned short)r;
}

// async global->LDS, 16B per lane; LDS dest = wave-uniform base + lane*16
typedef __attribute__((address_space(3))) unsigned int lds_u32_t;
typedef __attribute__((address_space(1))) const unsigned int glb_u32_t;
__device__ __forceinline__ void gload16(const void* g, void* l) {
  __builtin_amdgcn_global_load_lds((glb_u32_t*)g, (lds_u32_t*)l, 16, 0, 0);
}

// ---------------- workspace layout (bytes) ----------------
static const size_t OFF_PHI  = 0;                                         // 1 MB
static const size_t OFF_WA   = OFF_PHI  + (size_t)TE_*EH_*4;              // 64 KB
static const size_t OFF_HPRE = OFF_WA   + (size_t)B_*TD_*4;               // 1 MB
static const size_t OFF_EP   = OFF_HPRE + (size_t)B_*G_*4;                // 4 KB
static const size_t OFF_CP   = OFF_EP   + 4096;                           // spare
static const size_t OFF_ET   = ((OFF_CP + (size_t)B_*CC_*4 + 255)/256)*256; // X bf16 region
static const size_t OFF_STAT = OFF_ET + (size_t)B_*TE_*TD_*4;             // spare
static const size_t OFF_P    = ((OFF_STAT + (size_t)2*B_*TD_*4 + 255)/256)*256; // 16.7 MB bf16
static const size_t OFF_LT   = OFF_P  + (size_t)B_*TD_*TE_*2;             // 67 MB bf16
static const size_t OFF_WR   = OFF_LT + (size_t)B_*TE_*EH_*2;             // 2.6 MB bf16
static const size_t OFF_SP   = OFF_WR + (size_t)G_*KP_*2;                 // 512 KB fp32 partial sums
// scratch aliases inside P region (all consumed before k_bandmm writes P):
static const size_t OFF_PT   = OFF_P;                                     // 1 MB fp32 phi_w^T
static const size_t OFF_WT   = OFF_P + (size_t)2*1024*1024;               // 4 MB Whh^T fp32
static const size_t OFF_WAT  = OFF_P + (size_t)6*1024*1024;               // 256 KB Wa_w^T fp32

// ================= launch 1: fused preprocessing =================
// blocks [0,64)    : transpose phi_w [512][512] -> phiT
// blocks [64,320)  : transpose Whh  [2048][512] -> WhhT
// blocks [320,336) : transpose Wa_w [128][512]  -> WaT
// blocks [336,976) : Wih fp32 -> Wr bf16 [2048][640], rows nr = dh*4+gate
// blocks [976,9168): LSTM [b][t][e] -> LT [b][e][t] bf16
__global__ __launch_bounds__(256) void k_prep(
    const float* __restrict__ phi_w, float* __restrict__ phiT,
    const float* __restrict__ Whh,  float* __restrict__ WhhT,
    const float* __restrict__ Wa_w, float* __restrict__ WaT,
    const float* __restrict__ Wih,  unsigned short* __restrict__ Wr,
    const float* __restrict__ LSTM, unsigned short* __restrict__ LT) {
  __shared__ float tile[64][65];
  int blk = blockIdx.x, tid = threadIdx.x;
  if (blk < 336) {
    const float* src; float* dst; int R, i;
    if (blk < 64)       { src = phi_w; dst = phiT; R = 512;  i = blk; }
    else if (blk < 320) { src = Whh;   dst = WhhT; R = 2048; i = blk - 64; }
    else                { src = Wa_w;  dst = WaT;  R = 128;  i = blk - 320; }
    int nrb = R >> 6;
    int r0 = (i % nrb) * 64, c0 = (i / nrb) * 64;
    int r = tid >> 2, c16 = (tid & 3) * 16;
    const float4* s4 = (const float4*)(src + (size_t)(r0 + r)*512 + c0 + c16);
    float4 v0 = s4[0], v1 = s4[1], v2 = s4[2], v3 = s4[3];
    *(float4*)&tile[r][c16]    = v0;
    *(float4*)&tile[r][c16+4]  = v1;
    *(float4*)&tile[r][c16+8]  = v2;
    *(float4*)&tile[r][c16+12] = v3;
    __syncthreads();
    float o[16];
    #pragma unroll
    for (int j = 0; j < 16; ++j) o[j] = tile[c16+j][r];
    float* d = dst + (size_t)(c0 + r)*R + r0 + c16;
    *(float4*)d      = *(float4*)&o[0];
    *(float4*)(d+4)  = *(float4*)&o[4];
    *(float4*)(d+8)  = *(float4*)&o[8];
    *(float4*)(d+12) = *(float4*)&o[12];
  } else if (blk < 976) {
    int id = (blk - 336) * 256 + tid;     // 2048*80
    int nr = id / 80, c8 = (id % 80) * 8;
    int gate = nr & 3, dh = nr >> 2;
    const float* src = Wih + (size_t)(gate*DH_ + dh)*KX_;
    unsigned short o[8];
    #pragma unroll
    for (int j = 0; j < 8; ++j) {
      int col = c8 + j;
      o[j] = (col < KX_) ? f2bf(src[col]) : 0;
    }
    *(uint4*)(Wr + (size_t)nr*KP_ + c8) = *(uint4*)o;
  } else {
    int i = blk - 976;
    int e0 = (i & 7) * 64, t0 = ((i >> 3) & 7) * 64, b = i >> 6;
    int tt = tid >> 2, c16 = (tid & 3) * 16;
    const float4* src = (const float4*)(LSTM + ((size_t)b*TE_ + t0 + tt)*EH_ + e0 + c16);
    float4 v0 = src[0], v1 = src[1], v2 = src[2], v3 = src[3];
    *(float4*)&tile[tt][c16]    = v0;
    *(float4*)&tile[tt][c16+4]  = v1;
    *(float4*)&tile[tt][c16+8]  = v2;
    *(float4*)&tile[tt][c16+12] = v3;
    __syncthreads();
    int e = tid >> 2, t16 = (tid & 3) * 16;
    unsigned short o[16];
    #pragma unroll
    for (int j = 0; j < 16; ++j) o[j] = f2bf(tile[t16+j][e]);
    unsigned short* dst = LT + ((size_t)b*EH_ + e0 + e)*TE_ + t0 + t16;
    *(uint4*)dst     = *(uint4*)&o[0];
    *(uint4*)(dst+8) = *(uint4*)&o[8];
  }
}

// ================= launch 2: fused mid-tier =================
// blocks [0,16)    : phi exclusive scan + bias (each thread re-sums its prefix)
// blocks [16,48)   : wa[b][d] = tanh(s_i.Wa_w[d] + Wa_b[d]) * va_w[d] via WaT
// blocks [48,304)  : hpre[b][g] = bih+bhh + s_i.Whh[g] via WhhT
// blocks [304,528) : ep[b][k] = tanh(CNNs.w_cnn + s_i.w_s + wij_b)
__global__ __launch_bounds__(256) void k_mid(
    const float* __restrict__ phiT, const float* __restrict__ phi_b, float* __restrict__ phi,
    const float* __restrict__ WaT, const float* __restrict__ Wa_b,
    const float* __restrict__ va_w, float* __restrict__ wa,
    const float* __restrict__ WhhT, const float* __restrict__ bih,
    const float* __restrict__ bhh, float* __restrict__ hpre,
    const float* __restrict__ CNNs, const float* __restrict__ wij_w,
    const float* __restrict__ wij_b,
    const float* __restrict__ s_i, float* __restrict__ ep) {
  int blk = blockIdx.x, tid = threadIdx.x;
  if (blk < 16) {
    int e = (blk & 1) * 256 + tid;
    int z = blk >> 1;
    float off = phi_b[e];
    for (int t = 0; t < z*64; ++t) off += phiT[(size_t)t*EH_ + e];
    for (int t = z*64; t < z*64 + 64; ++t) {
      phi[(size_t)t*EH_ + e] = off;
      off += phiT[(size_t)t*EH_ + e];
    }
  } else if (blk < 48) {
    int lane = tid & 63, wv = tid >> 6;
    int b = (blk - 16) * 4 + wv;
    int d0 = lane * 2;
    const float2* w = (const float2*)WaT + lane;
    const float* s = s_i + (size_t)b*DH_;
    float ax = 0.f, ay = 0.f;
    #pragma unroll 8
    for (int k = 0; k < DH_; ++k) {
      float2 wv2 = w[(size_t)k*64];
      float x = s[k];
      ax += wv2.x * x; ay += wv2.y * x;
    }
    wa[b*TD_ + d0]     = tanhf_fast(ax + Wa_b[d0])     * va_w[d0];
    wa[b*TD_ + d0 + 1] = tanhf_fast(ay + Wa_b[d0 + 1]) * va_w[d0 + 1];
  } else if (blk < 304) {
    int i = blk - 48;
    int gq = (i & 1) * 256 + tid;
    int b  = i >> 1;
    const float4* w = (const float4*)WhhT + gq;
    const float* s = s_i + (size_t)b*DH_;
    float4 a = {0.f,0.f,0.f,0.f};
    #pragma unroll 8
    for (int k = 0; k < DH_; ++k) {
      float4 wv = w[(size_t)k*512];
      float x = s[k];
      a.x += wv.x*x; a.y += wv.y*x; a.z += wv.z*x; a.w += wv.w*x;
    }
    int g = gq * 4;
    float4 bi = *(const float4*)(bih + g);
    float4 bh = *(const float4*)(bhh + g);
    float4 o;
    o.x = a.x + bi.x + bh.x; o.y = a.y + bi.y + bh.y;
    o.z = a.z + bi.z + bh.z; o.w = a.w + bi.w + bh.w;
    *(float4*)(hpre + (size_t)b*G_ + g) = o;
  } else {
    int gw = (blk - 304) * 4 + (tid >> 6);
    int lane = tid & 63;
    if (gw < B_*KC_) {
      int b = gw / KC_, k = gw % KC_;
      const float* cr = CNNs + (size_t)(b*KC_ + k)*CC_;
      const float* wr = wij_w + (size_t)k*KX_;
      float acc = 0.f;
      for (int c = lane; c < CC_; c += 64) acc += cr[c] * wr[c];
      const float* sr = s_i + (size_t)b*DH_;
      const float* wsr = wr + CC_;
      #pragma unroll
      for (int j = 0; j < 8; ++j) { int h = lane + j*64; acc += sr[h] * wsr[h]; }
      #pragma unroll
      for (int m = 32; m; m >>= 1) acc += __shfl_xor(acc, m, 64);
      if (lane == 0) ep[gw] = tanhf_fast(acc + wij_b[k]);
    }
  }
}

// ======== launch 3: banded logits band-GEMM, fused softmax-exp ========
// Emits P = bf16(exp(val)) (transposed, unnormalized) + fp32 partial sums.
#define BMM_M 64
#define LDA_  40
#define LDB_  40
#define OTS_  132
__global__ __launch_bounds__(256) void k_bandmm(const float* __restrict__ LSTM,
                                                const float* __restrict__ phi,
                                                const float* __restrict__ Ua_w,
                                                const float* __restrict__ Ua_b,
                                                const float* __restrict__ va_w,
                                                const float* __restrict__ va_b,
                                                const float* __restrict__ wa,
                                                unsigned short* __restrict__ P,
                                                float* __restrict__ sums_p) {
  int t0 = blockIdx.x * BMM_M;   // 8 tiles
  int b  = blockIdx.y;           // 128
  int s_base = 321 - t0;
  __shared__ __align__(16) char smem[BMM_M * OTS_ * 4];   // 33.8 KB
  short* sA = (short*)smem;                 // [64][40]
  short* sB = (short*)(smem + BMM_M*LDA_*2);// [192][40]
  int tid = threadIdx.x;
  int wave = tid >> 6, lane = tid & 63;
  int quad = lane >> 4, l16 = lane & 15;

  f32x4 acc[4][3];
  #pragma unroll
  for (int m = 0; m < 4; ++m)
    #pragma unroll
    for (int n = 0; n < 3; ++n)
      acc[m][n] = (f32x4){0.f, 0.f, 0.f, 0.f};

  int arow = tid >> 2;
  int ach  = (tid & 3) * 8;
  int aq   = ach >> 2;

  const float4* baseL = (const float4*)(LSTM + ((size_t)b*TE_ + t0 + arow)*EH_);
  const float4* baseP = (const float4*)(phi + (size_t)(t0 + arow)*EH_);
  const float4* baseU[3];
  int brow[3], bch[3];
  #pragma unroll
  for (int c = 0; c < 3; ++c) {
    int idx = c*256 + tid;
    brow[c] = idx >> 2;
    bch[c]  = (idx & 3) * 8;
    int s = s_base + brow[c];
    int sc = s < 0 ? 0 : (s > 511 ? 511 : s);
    baseU[c] = (const float4*)(Ua_w + (size_t)sc*EH_ + bch[c]);
  }

  float4 l0 = baseL[aq], l1 = baseL[aq+1], p0 = baseP[aq], p1 = baseP[aq+1];
  float4 u0[3], u1[3];
  #pragma unroll
  for (int c = 0; c < 3; ++c) { u0[c] = baseU[c][0]; u1[c] = baseU[c][1]; }

  for (int k0 = 0; k0 < EH_; k0 += 32) {
    unsigned short at[8];
    at[0]=f2bf(l0.x*p0.x); at[1]=f2bf(l0.y*p0.y); at[2]=f2bf(l0.z*p0.z); at[3]=f2bf(l0.w*p0.w);
    at[4]=f2bf(l1.x*p1.x); at[5]=f2bf(l1.y*p1.y); at[6]=f2bf(l1.z*p1.z); at[7]=f2bf(l1.w*p1.w);
    unsigned short bt[3][8];
    #pragma unroll
    for (int c = 0; c < 3; ++c) {
      bt[c][0]=f2bf(u0[c].x); bt[c][1]=f2bf(u0[c].y); bt[c][2]=f2bf(u0[c].z); bt[c][3]=f2bf(u0[c].w);
      bt[c][4]=f2bf(u1[c].x); bt[c][5]=f2bf(u1[c].y); bt[c][6]=f2bf(u1[c].z); bt[c][7]=f2bf(u1[c].w);
    }
    if (k0 + 32 < EH_) {
      int q = (k0 + 32) >> 2;
      l0 = baseL[q+aq]; l1 = baseL[q+aq+1]; p0 = baseP[q+aq]; p1 = baseP[q+aq+1];
      #pragma unroll
      for (int c = 0; c < 3; ++c) { u0[c] = baseU[c][q]; u1[c] = baseU[c][q+1]; }
    }
    __syncthreads();
    *(uint4*)&sA[arow*LDA_ + ach] = *(uint4*)at;
    #pragma unroll
    for (int c = 0; c < 3; ++c)
      *(uint4*)&sB[brow[c]*LDB_ + bch[c]] = *(uint4*)bt[c];
    __syncthreads();
    bf16x8 bfr[3];
    #pragma unroll
    for (int n = 0; n < 3; ++n)
      bfr[n] = *(const bf16x8*)&sB[(l16 + (wave*3 + n)*16)*LDB_ + quad*8];
    #pragma unroll
    for (int m = 0; m < 4; ++m) {
      bf16x8 af = *(const bf16x8*)&sA[(l16 + m*16)*LDA_ + quad*8];
      #pragma unroll
      for (int n = 0; n < 3; ++n)
        acc[m][n] = __builtin_amdgcn_mfma_f32_16x16x32_bf16(af, bfr[n], acc[m][n], 0, 0, 0);
    }
  }

  __syncthreads();                 // sA/sB dead -> reuse smem as exp tile
  float* tileO = (float*)smem;     // [64][OTS_]
  float vb = va_b[0];
  #pragma unroll
  for (int n = 0; n < 3; ++n) {
    int s = s_base + wave*48 + n*16 + l16;
    float ub = (s >= 0 && s < TE_) ? Ua_b[s] : 0.f;
    float vw = (s >= 0 && s < TE_) ? va_w[TD_ + s] : 0.f;
    #pragma unroll
    for (int m = 0; m < 4; ++m) {
      #pragma unroll
      for (int r = 0; r < 4; ++r) {
        int tl = m*16 + quad*4 + r;
        int i = s + t0 + tl - 384;
        if (i >= 0 && i < TD_) {
          float val;
          if (s >= 0) val = tanhf_fast(acc[m][n][r] + ub) * vw + vb;
          else        val = wa[b*TD_ + s + 128] + vb;
          tileO[tl*OTS_ + i] = __expf(val);
        }
      }
    }
  }
  __syncthreads();
  if (tid < TD_) {
    float ssum = 0.f;
    #pragma unroll 8
    for (int tl = 0; tl < 64; ++tl) ssum += tileO[tl*OTS_ + tid];
    sums_p[((size_t)b*8 + blockIdx.x)*TD_ + tid] = ssum;
  }
  {
    int ii = tid >> 1, hf = tid & 1;
    unsigned short o[32];
    #pragma unroll
    for (int j = 0; j < 32; ++j)
      o[j] = f2bf(tileO[(hf*32 + j)*OTS_ + ii]);
    unsigned short* dst = P + ((size_t)b*TD_ + ii)*TE_ + t0 + hf*32;
    *(uint4*)dst      = *(uint4*)&o[0];
    *(uint4*)(dst+8)  = *(uint4*)&o[8];
    *(uint4*)(dst+16) = *(uint4*)&o[16];
    *(uint4*)(dst+24) = *(uint4*)&o[24];
  }
}

// ======== launch 4: ci GEMM + local sinv + (e0==0) cp/X-fill ========
// X[b*128+i][e] = (1/sum_t expP) * sum_t P[b][i][t]*LT[b][e][t]
// Each block reduces its b's sums_p slice locally (4 KB); the e0==0 block
// additionally computes the CNN context c_p and fills X[:,512:640].
#define CI_LD 40
__global__ __launch_bounds__(256) void k_ci2(const unsigned short* __restrict__ P,
                                             const unsigned short* __restrict__ LT,
                                             const float* __restrict__ sums_p,
                                             const float* __restrict__ ep,
                                             const float* __restrict__ CNNs,
                                             unsigned short* __restrict__ X) {
  int b = blockIdx.x, e0 = blockIdx.y * 128;
  __shared__ short sA[128 * CI_LD];
  __shared__ short sB[128 * CI_LD];
  __shared__ float svL[TD_];
  __shared__ float red2[256];
  int tid = threadIdx.x;
  int wave = tid >> 6, lane = tid & 63, quad = lane >> 4, l16 = lane & 15;
  int wm = wave >> 1, wn = wave & 1;
  int row = tid >> 1, ho = (tid & 1) * 16;

  if (tid < TD_) {
    float s = 0.f;
    #pragma unroll
    for (int z = 0; z < 8; ++z) s += sums_p[((size_t)b*8 + z)*TD_ + tid];
    svL[tid] = 1.f / s;
  }

  const unsigned short* pa = P + ((size_t)b*TD_ + row)*TE_ + ho;
  const unsigned short* pb = LT + ((size_t)b*EH_ + e0 + row)*TE_ + ho;

  f32x4 acc[4][4];
  #pragma unroll
  for (int m = 0; m < 4; ++m)
    #pragma unroll
    for (int n = 0; n < 4; ++n)
      acc[m][n] = (f32x4){0.f, 0.f, 0.f, 0.f};

  uint4 a0 = *(const uint4*)pa, a1 = *(const uint4*)(pa + 8);
  uint4 b0 = *(const uint4*)pb, b1 = *(const uint4*)(pb + 8);

  for (int k0 = 0; k0 < TE_; k0 += 32) {
    uint4 na0, na1, nb0, nb1;
    if (k0 + 32 < TE_) {
      na0 = *(const uint4*)(pa + k0 + 32); na1 = *(const uint4*)(pa + k0 + 40);
      nb0 = *(const uint4*)(pb + k0 + 32); nb1 = *(const uint4*)(pb + k0 + 40);
    }
    __syncthreads();
    *(uint4*)&sA[row*CI_LD + ho]     = a0;
    *(uint4*)&sA[row*CI_LD + ho + 8] = a1;
    *(uint4*)&sB[row*CI_LD + ho]     = b0;
    *(uint4*)&sB[row*CI_LD + ho + 8] = b1;
    __syncthreads();
    bf16x8 bfr[4];
    #pragma unroll
    for (int n = 0; n < 4; ++n)
      bfr[n] = *(const bf16x8*)&sB[(wn*64 + n*16 + l16)*CI_LD + quad*8];
    #pragma unroll
    for (int m = 0; m < 4; ++m) {
      bf16x8 af = *(const bf16x8*)&sA[(wm*64 + m*16 + l16)*CI_LD + quad*8];
      #pragma unroll
      for (int n = 0; n < 4; ++n)
        acc[m][n] = __builtin_amdgcn_mfma_f32_16x16x32_bf16(af, bfr[n], acc[m][n], 0, 0, 0);
    }
    a0 = na0; a1 = na1; b0 = nb0; b1 = nb1;
  }

  #pragma unroll
  for (int m = 0; m < 4; ++m) {
    int i = wm*64 + m*16 + quad*4;
    float i0 = svL[i], i1 = svL[i+1], i2 = svL[i+2], i3 = svL[i+3];
    #pragma unroll
    for (int n = 0; n < 4; ++n) {
      int e = e0 + wn*64 + n*16 + l16;
      unsigned short* xp = X + ((size_t)b*TD_ + i)*KP_ + e;
      xp[0]              = f2bf(acc[m][n][0] * i0);
      xp[(size_t)KP_]    = f2bf(acc[m][n][1] * i1);
      xp[(size_t)2*KP_]  = f2bf(acc[m][n][2] * i2);
      xp[(size_t)3*KP_]  = f2bf(acc[m][n][3] * i3);
    }
  }

  if (e0 == 0) {   // block-uniform branch: cp part (ref: exp(ep)/sum(ep) GLOBAL sum)
    __syncthreads();
    float p = 0.f;
    for (int j = tid; j < B_*KC_; j += 256) p += ep[j];
    red2[tid] = p;
    __syncthreads();
    for (int off = 128; off > 0; off >>= 1) {
      if (tid < off) red2[tid] += red2[tid + off];
      __syncthreads();
    }
    float S = red2[0];
    int c = tid;
    if (c < 128) {
      float apl[KC_];
      #pragma unroll
      for (int k = 0; k < KC_; ++k) apl[k] = __expf(ep[b*KC_ + k]) / S;
      float acc2 = 0.f;
      if (c < CC_) {
        #pragma unroll
        for (int k = 0; k < KC_; ++k)
          acc2 += apl[k] * CNNs[(size_t)(b*KC_ + k)*CC_ + c];
      }
      unsigned short o = (c < CC_) ? f2bf(acc2) : 0;
      unsigned short* xb = X + (size_t)b*TD_*KP_ + EH_ + c;
      for (int i = 0; i < TD_; ++i)
        xb[(size_t)i*KP_] = o;
    }
  }
}

// ======== launch 5: 256x256x(BK=64) gates GEMM + fused LSTM cell ========
__global__ __launch_bounds__(512, 2) void k_gates8(const unsigned short* __restrict__ Wr,
                                                   const unsigned short* __restrict__ X,
                                                   const float* __restrict__ hpre,
                                                   const float* __restrict__ m_i,
                                                   float* __restrict__ out) {
  __shared__ short lds[4 * 256 * 64];       // 128 KiB
  const int g0  = blockIdx.x * 256;
  const int mi0 = blockIdx.y * 256;
  const int tid  = threadIdx.x;
  const int wave = tid >> 6, lane = tid & 63;
  const int l16 = lane & 15, quad = lane >> 4;
  const int wr = wave >> 2, wc = wave & 3;

  const int srow8 = lane >> 3;
  const int sch   = (lane & 7) ^ srow8;
  const unsigned short* gA = Wr + (size_t)(g0  + wave*8 + srow8) * KP_ + sch*8;
  const unsigned short* gB = X  + (size_t)(mi0 + wave*8 + srow8) * KP_ + sch*8;
  short* lA0 = lds;
  short* lB0 = lds + 16384;
  short* lA1 = lds + 32768;
  short* lB1 = lds + 49152;

  f32x4 acc[8][4];
  #pragma unroll
  for (int m = 0; m < 8; ++m)
    #pragma unroll
    for (int n = 0; n < 4; ++n) acc[m][n] = (f32x4){0.f, 0.f, 0.f, 0.f};

  auto stage = [&](int kt, int bf) {
    short* la = bf ? lA1 : lA0;
    short* lb = bf ? lB1 : lB0;
    const unsigned short* ga = gA + kt*64;
    const unsigned short* gb = gB + kt*64;
    #pragma unroll
    for (int r = 0; r < 4; ++r) {
      gload16(ga + (size_t)r*64*KP_, la + (r*8 + wave)*512);
      gload16(gb + (size_t)r*64*KP_, lb + (r*8 + wave)*512);
    }
  };

  stage(0, 0);
  __syncthreads();

  const int x7 = l16 & 7;
  for (int kt = 0; kt < GNT; ++kt) {
    const int cur = kt & 1;
    if (kt + 1 < GNT) stage(kt + 1, cur ^ 1);
    const short* la = cur ? lA1 : lA0;
    const short* lb = cur ? lB1 : lB0;
    #pragma unroll
    for (int ks = 0; ks < 2; ++ks) {
      const int ck = ((((ks << 2) | quad) ^ x7) << 3);
      bf16x8 bv[4];
      #pragma unroll
      for (int n = 0; n < 4; ++n)
        bv[n] = *(const bf16x8*)&lb[(wc*64 + n*16 + l16)*64 + ck];
      #pragma unroll
      for (int qm = 0; qm < 2; ++qm) {
        bf16x8 av[4];
        #pragma unroll
        for (int m = 0; m < 4; ++m)
          av[m] = *(const bf16x8*)&la[(wr*128 + qm*64 + m*16 + l16)*64 + ck];
        __builtin_amdgcn_s_setprio(1);
        #pragma unroll
        for (int m = 0; m < 4; ++m)
          #pragma unroll
          for (int n = 0; n < 4; ++n)
            acc[qm*4 + m][n] = __builtin_amdgcn_mfma_f32_16x16x32_bf16(av[m], bv[n], acc[qm*4 + m][n], 0, 0, 0);
        __builtin_amdgcn_s_setprio(0);
      }
    }
    __syncthreads();
  }

  const int bb = (mi0 >> 7) + (wc >> 1);
  const float* hp = hpre + (size_t)bb * G_;
  #pragma unroll
  for (int M = 0; M < 8; ++M) {
    const int dh = (g0 >> 2) + wr*32 + M*4 + quad;
    float h0 = hp[dh], h1 = hp[DH_ + dh], h2 = hp[2*DH_ + dh], h3 = hp[3*DH_ + dh];
    float miv = m_i[(size_t)bb*DH_ + dh];
    #pragma unroll
    for (int n = 0; n < 4; ++n) {
      int mi = mi0 + wc*64 + n*16 + l16;
      float ig = acc[M][n][0] + h0;
      float fg = acc[M][n][1] + h1;
      float gg = acc[M][n][2] + h2;
      float og = acc[M][n][3] + h3;
      float c  = sigm(fg)*miv + sigm(ig)*tanhf_fast(gg);
      float h  = sigm(og)*tanhf_fast(c);
      out[(size_t)mi*DH_ + dh] = h;
    }
  }
}

extern "C" void kernel_launch(void* const* d_in, const int* in_sizes, int n_in,
                              void* d_out, int out_size, void* d_ws, size_t ws_size,
                              hipStream_t stream) {
  (void)in_sizes; (void)n_in; (void)out_size; (void)ws_size;
  const float* LSTM  = (const float*)d_in[0];
  const float* CNNs  = (const float*)d_in[1];
  const float* Wa_w  = (const float*)d_in[2];
  const float* Wa_b  = (const float*)d_in[3];
  const float* Ua_w  = (const float*)d_in[4];
  const float* Ua_b  = (const float*)d_in[5];
  const float* va_w  = (const float*)d_in[6];
  const float* va_b  = (const float*)d_in[7];
  const float* phi_w = (const float*)d_in[8];
  const float* phi_b = (const float*)d_in[9];
  const float* Wih   = (const float*)d_in[10];
  const float* Whh   = (const float*)d_in[11];
  const float* bih   = (const float*)d_in[12];
  const float* bhh   = (const float*)d_in[13];
  const float* wij_w = (const float*)d_in[14];
  const float* wij_b = (const float*)d_in[15];
  const float* s_i   = (const float*)d_in[16];
  const float* m_i   = (const float*)d_in[17];
  float* out = (float*)d_out;
  char* ws = (char*)d_ws;

  float* phi  = (float*)(ws + OFF_PHI);
  float* wa   = (float*)(ws + OFF_WA);
  float* hpre = (float*)(ws + OFF_HPRE);
  float* ep   = (float*)(ws + OFF_EP);
  unsigned short* X  = (unsigned short*)(ws + OFF_ET);
  unsigned short* P  = (unsigned short*)(ws + OFF_P);
  unsigned short* LT = (unsigned short*)(ws + OFF_LT);
  unsigned short* Wr = (unsigned short*)(ws + OFF_WR);
  float* sums_p      = (float*)(ws + OFF_SP);
  float* phiT        = (float*)(ws + OFF_PT);            // aliases P region (pre-bandmm)
  float* WhhT        = (float*)(ws + OFF_WT);            // aliases P region (pre-bandmm)
  float* WaT         = (float*)(ws + OFF_WAT);           // aliases P region (pre-bandmm)

  k_prep  <<<dim3(9168),  dim3(256), 0, stream>>>(phi_w, phiT, Whh, WhhT, Wa_w, WaT,
                                                  Wih, Wr, LSTM, LT);
  k_mid   <<<dim3(528),   dim3(256), 0, stream>>>(phiT, phi_b, phi,
                                                  WaT, Wa_b, va_w, wa,
                                                  WhhT, bih, bhh, hpre,
                                                  CNNs, wij_w, wij_b, s_i, ep);
  k_bandmm<<<dim3(8,128), dim3(256), 0, stream>>>(LSTM, phi, Ua_w, Ua_b, va_w, va_b,
                                                  wa, P, sums_p);
  k_ci2   <<<dim3(128,4), dim3(256), 0, stream>>>(P, LT, sums_p, ep, CNNs, X);
  k_gates8<<<dim3(8,64),  dim3(512), 0, stream>>>(Wr, X, hpre, m_i, out);
}